// Round 1
// baseline (16.515 us; speedup 1.0000x reference)
//
#include <hip/hip_runtime.h>
#include <math.h>

#define Bn 16
#define Nn 3072
#define Cn 192
#define TOLf 1e-4f
#define MAX_IT 100
#define EPSf 1e-12f

// One block per batch. Newton iteration on lmd[C] with analytic tridiagonal
// Jacobian (chain constraints: idx_i=c, idx_j=c+1) solved by PCR in LDS.
__global__ __launch_bounds__(256) void bme_solver_kernel(
    const float* __restrict__ pos, const float* __restrict__ mas,
    const float* __restrict__ dtm, const float* __restrict__ col_jac,
    const float* __restrict__ col_cen, const float* __restrict__ lmd_tmp,
    const int* __restrict__ idx_i, const int* __restrict__ idx_j,
    float* __restrict__ out_lmd, float* __restrict__ out_con)
{
    const int b   = blockIdx.x;
    const int tid = threadIdx.x;

    __shared__ float jacI[Cn][3], jacJ[Cn][3], baseD[Cn][3];
    __shared__ float imI[Cn], imJ[Cn], cen[Cn], lmd[Cn], dst[Cn];
    __shared__ float frcA[Cn + 1][3];
    __shared__ float pa[256], pb[256], pc[256], pd[256];
    __shared__ float qa[256], qb[256], qc[256], qd[256];
    __shared__ float red[256];

    const float dt  = dtm[b];
    const float dt2 = dt * dt;

    // ---- load the sparse structure (only nonzero jac entries) ----
    for (int c = tid; c < Cn; c += 256) {
        const int ii = idx_i[c], jj = idx_j[c];
        const size_t jb = ((size_t)(b * Cn + c)) * Nn;
        for (int k = 0; k < 3; ++k) {
            jacI[c][k]  = col_jac[(jb + ii) * 3 + k];
            jacJ[c][k]  = col_jac[(jb + jj) * 3 + k];
            baseD[c][k] = pos[((size_t)b * Nn + ii) * 3 + k]
                        - pos[((size_t)b * Nn + jj) * 3 + k];
        }
        imI[c] = dt2 / mas[b * Nn + ii];
        imJ[c] = dt2 / mas[b * Nn + jj];
        cen[c] = col_cen[b * Cn + c];
        lmd[c] = 0.f;
    }
    __syncthreads();

    int it = 0;
    while (true) {
        // ---- gather constraint forces at chain atoms 0..C ----
        for (int a = tid; a <= Cn; a += 256) {
            float fx = 0.f, fy = 0.f, fz = 0.f;
            if (a < Cn) {
                const float l = lmd[a];
                fx -= l * jacI[a][0]; fy -= l * jacI[a][1]; fz -= l * jacI[a][2];
            }
            if (a >= 1) {
                const float l = lmd[a - 1];
                fx -= l * jacJ[a-1][0]; fy -= l * jacJ[a-1][1]; fz -= l * jacJ[a-1][2];
            }
            frcA[a][0] = fx; frcA[a][1] = fy; frcA[a][2] = fz;
        }
        __syncthreads();

        // ---- residual + tridiagonal Jacobian row per constraint ----
        if (tid < Cn) {
            const float dx = baseD[tid][0] + imI[tid]*frcA[tid][0] - imJ[tid]*frcA[tid+1][0];
            const float dy = baseD[tid][1] + imI[tid]*frcA[tid][1] - imJ[tid]*frcA[tid+1][1];
            const float dz = baseD[tid][2] + imI[tid]*frcA[tid][2] - imJ[tid]*frcA[tid+1][2];
            const float dd  = sqrtf(dx*dx + dy*dy + dz*dz + EPSf);
            const float inv = 1.0f / dd;
            dst[tid] = dd;
            const float con = dd - cen[tid];

            // diag: d(d)/d(lmd_c) = -imI*jacI[c] + imJ*jacJ[c]
            const float gx = -imI[tid]*jacI[tid][0] + imJ[tid]*jacJ[tid][0];
            const float gy = -imI[tid]*jacI[tid][1] + imJ[tid]*jacJ[tid][1];
            const float gz = -imI[tid]*jacI[tid][2] + imJ[tid]*jacJ[tid][2];
            const float diag = (dx*gx + dy*gy + dz*gz) * inv;

            float sub = 0.f, sup = 0.f;
            if (tid > 0) {        // d(d)/d(lmd_{c-1}) = -imI*jacJ[c-1]
                const float sx = -imI[tid]*jacJ[tid-1][0];
                const float sy = -imI[tid]*jacJ[tid-1][1];
                const float sz = -imI[tid]*jacJ[tid-1][2];
                sub = (dx*sx + dy*sy + dz*sz) * inv;
            }
            if (tid < Cn - 1) {   // d(d)/d(lmd_{c+1}) = +imJ*jacI[c+1]
                const float px = imJ[tid]*jacI[tid+1][0];
                const float py = imJ[tid]*jacI[tid+1][1];
                const float pz = imJ[tid]*jacI[tid+1][2];
                sup = (dx*px + dy*py + dz*pz) * inv;
            }
            pa[tid] = sub; pb[tid] = diag; pc[tid] = sup; pd[tid] = con;
            red[tid] = fabsf(con);
        } else {
            pa[tid] = 0.f; pb[tid] = 1.f; pc[tid] = 0.f; pd[tid] = 0.f;
            red[tid] = 0.f;
        }
        __syncthreads();

        // ---- block max-reduce |con| ----
        for (int off = 128; off > 0; off >>= 1) {
            if (tid < off) red[tid] = fmaxf(red[tid], red[tid + off]);
            __syncthreads();
        }
        const float maxcon = red[0];
        __syncthreads();

        if (maxcon < TOLf || it >= MAX_IT) break;

        // ---- PCR tridiagonal solve (8 steps for n=256) ----
        float *Aa = pa, *Ab = pb, *Ac = pc, *Ad = pd;
        float *Ba = qa, *Bb = qb, *Bc = qc, *Bd = qd;
        for (int s = 1; s < 256; s <<= 1) {
            const float ai = Aa[tid], bi = Ab[tid], ci = Ac[tid], di = Ad[tid];
            const int im = tid - s, ip = tid + s;
            float am, bm, cm, dm, ap, bp, cp, dp;
            if (im >= 0) { am = Aa[im]; bm = Ab[im]; cm = Ac[im]; dm = Ad[im]; }
            else         { am = 0.f;   bm = 1.f;    cm = 0.f;    dm = 0.f;   }
            if (ip < 256){ ap = Aa[ip]; bp = Ab[ip]; cp = Ac[ip]; dp = Ad[ip]; }
            else         { ap = 0.f;   bp = 1.f;    cp = 0.f;    dp = 0.f;   }
            const float alpha = -ai / bm;
            const float gamma = -ci / bp;
            Ba[tid] = alpha * am;
            Bc[tid] = gamma * cp;
            Bb[tid] = bi + alpha * cm + gamma * ap;
            Bd[tid] = di + alpha * dm + gamma * dp;
            __syncthreads();
            float* t;
            t = Aa; Aa = Ba; Ba = t;  t = Ab; Ab = Bb; Bb = t;
            t = Ac; Ac = Bc; Bc = t;  t = Ad; Ad = Bd; Bd = t;
        }
        if (tid < Cn) lmd[tid] -= Ad[tid] / Ab[tid];
        __syncthreads();
        ++it;
    }

    // ---- write lmd and final constraint value (con + cen == dist) ----
    if (tid < Cn) {
        const int o = b * Cn + tid;
        out_lmd[o] = lmd_tmp[o] + lmd[tid];
        out_con[o] = dst[tid];
    }
}

// Streaming pos/mom update. frc nonzero only at chain atoms n in [0, C].
__global__ __launch_bounds__(256) void bme_update_kernel(
    const float* __restrict__ pos, const float* __restrict__ mom,
    const float* __restrict__ mas, const float* __restrict__ dtm,
    const float* __restrict__ col_jac,
    const float* __restrict__ out_lmd, const float* __restrict__ lmd_tmp,
    float* __restrict__ out_pos, float* __restrict__ out_mom)
{
    const int idx = blockIdx.x * blockDim.x + threadIdx.x;  // atom id in [0, B*N)
    if (idx >= Bn * Nn) return;
    const int b = idx / Nn;
    const int n = idx - b * Nn;

    const float dt  = dtm[b];
    const float dt2 = dt * dt;

    float fx = 0.f, fy = 0.f, fz = 0.f;
    if (n < Cn) {  // constraint c=n has idx_i==n
        const float l = out_lmd[b * Cn + n] - lmd_tmp[b * Cn + n];
        const size_t jb = (((size_t)(b * Cn + n)) * Nn + n) * 3;
        fx -= l * col_jac[jb + 0];
        fy -= l * col_jac[jb + 1];
        fz -= l * col_jac[jb + 2];
    }
    if (n >= 1 && n <= Cn) {  // constraint c=n-1 has idx_j==n
        const int c = n - 1;
        const float l = out_lmd[b * Cn + c] - lmd_tmp[b * Cn + c];
        const size_t jb = (((size_t)(b * Cn + c)) * Nn + n) * 3;
        fx -= l * col_jac[jb + 0];
        fy -= l * col_jac[jb + 1];
        fz -= l * col_jac[jb + 2];
    }

    const size_t p  = (size_t)idx * 3;
    const float  im = dt2 / mas[idx];
    out_pos[p + 0] = pos[p + 0] + fx * im;
    out_pos[p + 1] = pos[p + 1] + fy * im;
    out_pos[p + 2] = pos[p + 2] + fz * im;
    out_mom[p + 0] = mom[p + 0] + fx * dt;
    out_mom[p + 1] = mom[p + 1] + fy * dt;
    out_mom[p + 2] = mom[p + 2] + fz * dt;
}

extern "C" void kernel_launch(void* const* d_in, const int* in_sizes, int n_in,
                              void* d_out, int out_size, void* d_ws, size_t ws_size,
                              hipStream_t stream) {
    const float* pos     = (const float*)d_in[0];
    const float* mom     = (const float*)d_in[1];
    const float* mas     = (const float*)d_in[2];
    const float* dtm     = (const float*)d_in[3];
    const float* col_jac = (const float*)d_in[4];
    const float* col_cen = (const float*)d_in[5];
    const float* lmd_tmp = (const float*)d_in[6];
    const int*   idx_i   = (const int*)d_in[7];
    const int*   idx_j   = (const int*)d_in[8];

    float* out     = (float*)d_out;
    float* out_pos = out;                         // [B,N,3]
    float* out_mom = out + (size_t)Bn * Nn * 3;   // [B,N,3]
    float* out_lmd = out + (size_t)2 * Bn * Nn * 3;  // [B,C]
    float* out_con = out_lmd + Bn * Cn;              // [B,C]

    bme_solver_kernel<<<Bn, 256, 0, stream>>>(
        pos, mas, dtm, col_jac, col_cen, lmd_tmp, idx_i, idx_j,
        out_lmd, out_con);

    bme_update_kernel<<<(Bn * Nn + 255) / 256, 256, 0, stream>>>(
        pos, mom, mas, dtm, col_jac, out_lmd, lmd_tmp, out_pos, out_mom);
}